// Round 8
// baseline (2755.024 us; speedup 1.0000x reference)
//
#include <hip/hip_runtime.h>

#define HS    128
#define INP   23
#define NGATE 512
#define TLEN  1024
#define BATCH 512
#define MROWS 16
#define NWG   (BATCH / MROWS)   // 32 workgroups

typedef short  bf8   __attribute__((ext_vector_type(8)));   // 8 bf16 (4 VGPR)
typedef float  f32x4 __attribute__((ext_vector_type(4)));

__device__ __forceinline__ float fexp(float x) {
    return __builtin_amdgcn_exp2f(x * 1.4426950408889634f);
}
__device__ __forceinline__ float fsigmoid(float x) {
    return __builtin_amdgcn_rcpf(1.0f + fexp(-x));
}
__device__ __forceinline__ float ftanh(float x) {
    return 2.0f * fsigmoid(2.0f * x) - 1.0f;
}
__device__ __forceinline__ short bf16r(float x) {   // round-to-nearest-even
    unsigned u = __float_as_uint(x);
    u += 0x7fffu + ((u >> 16) & 1u);
    return (short)(u >> 16);
}

// ---------------------------------------------------------------------------
// Setup: repack U[128][512] and W[24][512] (f32) into bf16 B-fragment order.
//   Upk[cb<32][s<4][lane<64][e<8] = U[s*32 + 8*(lane>>4)+e][cb*16 + (lane&15)]
//   Wpk[cb<32][lane<64][e<8]      = W[8*(lane>>4)+e][cb*16+(lane&15)], k>=24 -> 0
// Runs every launch (d_ws is re-poisoned). Total 160 KB into d_ws.
// ---------------------------------------------------------------------------
__global__ void repack_kernel(const float* __restrict__ W,
                              const float* __restrict__ U,
                              short* __restrict__ ws)
{
    const int id = blockIdx.x * 256 + threadIdx.x;
    short tmp[8];
    if (id < 8192) {                       // Upk: 32*4*64 frag-rows
        const int cb = id >> 8, s = (id >> 6) & 3, l = id & 63;
        const int col = cb * 16 + (l & 15);
        const int kb  = s * 32 + ((l >> 4) << 3);
        #pragma unroll
        for (int e = 0; e < 8; ++e) tmp[e] = bf16r(U[(kb + e) * NGATE + col]);
        *(bf8*)(ws + id * 8) = *(const bf8*)tmp;
    } else if (id < 10240) {               // Wpk: 32*64 frag-rows
        const int id2 = id - 8192;
        const int cb = id2 >> 6, l = id2 & 63;
        const int col = cb * 16 + (l & 15);
        const int kb  = (l >> 4) << 3;
        #pragma unroll
        for (int e = 0; e < 8; ++e)
            tmp[e] = (kb + e < 24) ? bf16r(W[(kb + e) * NGATE + col]) : (short)0;
        *(bf8*)(ws + 65536 + id2 * 8) = *(const bf8*)tmp;
    }
}

// ---------------------------------------------------------------------------
// Main: 32 WGs x 512 threads (8 waves). WG owns batch rows [wg*16, wg*16+16).
// Wave w owns gate cols {g*128 + w*16 .. +16} for g=0..3  ->  i,f,g,o for
// h-col j = w*16+(lane&15) all live in the SAME lane's accumulators.
// B-frags stream from L2 every step (160 KB working set, L2-resident/XCD);
// h kept bf16 in LDS in A-frag order; c fp32 in registers.
// ---------------------------------------------------------------------------
__global__ __launch_bounds__(512)
void lstm_mfma(const float* __restrict__ points,
               const float* __restrict__ times,
               const float* __restrict__ bias,
               const float* __restrict__ Wc,
               const float* __restrict__ bc,
               float* __restrict__ out,
               const short* __restrict__ ws)
{
    const int wg  = blockIdx.x;
    const int tid = threadIdx.x;
    const int w   = tid >> 6;          // wave 0..7
    const int l   = tid & 63;          // lane

    __shared__ __align__(16) short hfrag[2][4][64][8];  // 8 KB  (A-frag layout)
    __shared__ __align__(16) short xfrag[2][64][8];     // 2 KB  (A-frag layout)
    __shared__ float opart[2][8][MROWS][2];             // 2 KB

    const int j = w * 16 + (l & 15);                    // this lane's h column
    const float wc0 = Wc[2 * j], wc1 = Wc[2 * j + 1];
    const float bc0 = bc[0], bc1 = bc[1];
    float bg[4];
    #pragma unroll
    for (int gi = 0; gi < 4; ++gi) bg[gi] = bias[gi * 128 + j];

    // per-thread fragment base pointers (cb = gi*8 + w)
    const short* upk_td = ws + w * 2048 + l * 8;            // + gi*16384 + s*512
    const short* wpk_td = ws + 65536 + w * 512 + l * 8;     // + gi*4096

    // ---- init LDS ----
    // zero hfrag[0] (h0 = 0): 2048 shorts = 1024 ints
    {
        int* p = (int*)&hfrag[0][0][0][0];
        p[tid] = 0; p[tid + 512] = 0;
        // zero both xfrag buffers (pad lanes 48-63 stay 0 forever)
        ((int*)&xfrag[0][0][0])[tid] = 0;
    }
    // stage x(t=0): threads 0..383 load one (row r, feature f)
    if (tid < MROWS * 24) {
        const int r = tid / 24, f = tid % 24;
        const int b = wg * MROWS + r;
        const float v = (f < INP) ? points[((size_t)b * TLEN + 0) * INP + f]
                                  : times[(size_t)b * TLEN + 0];
        xfrag[0][r | ((f >> 3) << 4)][f & 7] = bf16r(v);
    }
    __syncthreads();

    float c4[4] = {0.0f, 0.0f, 0.0f, 0.0f};
    const int sH   = w >> 1;                              // h-write k-step
    const int cgrp = ((w & 1) << 1) | ((l & 15) >> 3);    // h-write k-subgroup

    for (int t = 0; t < TLEN; ++t) {
        const int cur = t & 1, nxt = cur ^ 1;

        // 1. finish output row t-1 (opart written last iter, barrier-protected)
        if (t > 0 && tid < 64 && tid < 2 * MROWS) {
            const int r = tid >> 1, o = tid & 1;
            float v = o ? bc1 : bc0;
            #pragma unroll
            for (int wv = 0; wv < 8; ++wv) v += opart[(t - 1) & 1][wv][r][o];
            out[(((size_t)(wg * MROWS + r)) * TLEN + (t - 1)) * 2 + o] = fsigmoid(v);
        }

        // 2. prefetch x(t+1) into xfrag[nxt]
        if (t + 1 < TLEN && tid < MROWS * 24) {
            const int r = tid / 24, f = tid % 24;
            const int b = wg * MROWS + r;
            const float v = (f < INP) ? points[((size_t)b * TLEN + (t + 1)) * INP + f]
                                      : times[(size_t)b * TLEN + (t + 1)];
            xfrag[nxt][r | ((f >> 3) << 4)][f & 7] = bf16r(v);
        }

        // 3. A-fragments from LDS (conflict-free: lane l reads its own 16B row)
        const bf8 xa  = *(const bf8*)&xfrag[cur][l][0];
        const bf8 ha0 = *(const bf8*)&hfrag[cur][0][l][0];
        const bf8 ha1 = *(const bf8*)&hfrag[cur][1][l][0];
        const bf8 ha2 = *(const bf8*)&hfrag[cur][2][l][0];
        const bf8 ha3 = *(const bf8*)&hfrag[cur][3][l][0];

        // 4. B-fragments from L2 + MFMA. Opaque pointers: loads must stay
        //    per-iteration (r1/r7 lesson: hoisting -> giant live set -> remat/spill).
        const short* up = upk_td;  asm volatile("" : "+v"(up));
        const short* wp = wpk_td;  asm volatile("" : "+v"(wp));
        f32x4 acc[4];
        #pragma unroll
        for (int gi = 0; gi < 4; ++gi) {
            const bf8 wf = *(const bf8*)(wp + gi * 4096);
            const bf8 u0 = *(const bf8*)(up + gi * 16384 + 0 * 512);
            const bf8 u1 = *(const bf8*)(up + gi * 16384 + 1 * 512);
            const bf8 u2 = *(const bf8*)(up + gi * 16384 + 2 * 512);
            const bf8 u3 = *(const bf8*)(up + gi * 16384 + 3 * 512);
            f32x4 a = {bg[gi], bg[gi], bg[gi], bg[gi]};   // bias pre-seeded
            a = __builtin_amdgcn_mfma_f32_16x16x32_bf16(xa,  wf, a, 0, 0, 0);
            a = __builtin_amdgcn_mfma_f32_16x16x32_bf16(ha0, u0, a, 0, 0, 0);
            a = __builtin_amdgcn_mfma_f32_16x16x32_bf16(ha1, u1, a, 0, 0, 0);
            a = __builtin_amdgcn_mfma_f32_16x16x32_bf16(ha2, u2, a, 0, 0, 0);
            a = __builtin_amdgcn_mfma_f32_16x16x32_bf16(ha3, u3, a, 0, 0, 0);
            acc[gi] = a;
        }

        // 5. activations + cell update (fp32, in-register; rows 4*(l>>4)+q)
        float h4[4];
        #pragma unroll
        for (int q = 0; q < 4; ++q) {
            const float ig = fsigmoid(acc[0][q]);
            const float fg = fsigmoid(acc[1][q]);
            const float gg = ftanh(acc[2][q]);
            const float og = fsigmoid(acc[3][q]);
            c4[q] = fg * c4[q] + ig * gg;
            h4[q] = og * ftanh(c4[q]);
        }

        // 6. output-projection partials: reduce over the 16 cols of this wave
        {
            float p0[4], p1[4];
            #pragma unroll
            for (int q = 0; q < 4; ++q) { p0[q] = h4[q] * wc0; p1[q] = h4[q] * wc1; }
            #pragma unroll
            for (int off = 1; off < 16; off <<= 1) {
                #pragma unroll
                for (int q = 0; q < 4; ++q) {
                    p0[q] += __shfl_xor(p0[q], off);
                    p1[q] += __shfl_xor(p1[q], off);
                }
            }
            if ((l & 15) == 0) {
                const int rb = (l >> 4) * 4;
                #pragma unroll
                for (int q = 0; q < 4; ++q) {
                    opart[cur][w][rb + q][0] = p0[q];
                    opart[cur][w][rb + q][1] = p1[q];
                }
            }
        }

        // 7. publish h(t+1) as bf16 A-fragments
        #pragma unroll
        for (int q = 0; q < 4; ++q) {
            const int row = 4 * (l >> 4) + q;
            hfrag[nxt][sH][row | (cgrp << 4)][l & 7] = bf16r(h4[q]);
        }

        __syncthreads();   // the single per-step barrier
    }

    // epilogue: output row TLEN-1
    if (tid < 2 * MROWS) {
        const int r = tid >> 1, o = tid & 1;
        float v = o ? bc1 : bc0;
        #pragma unroll
        for (int wv = 0; wv < 8; ++wv) v += opart[(TLEN - 1) & 1][wv][r][o];
        out[(((size_t)(wg * MROWS + r)) * TLEN + (TLEN - 1)) * 2 + o] = fsigmoid(v);
    }
}

extern "C" void kernel_launch(void* const* d_in, const int* in_sizes, int n_in,
                              void* d_out, int out_size, void* d_ws, size_t ws_size,
                              hipStream_t stream) {
    const float* points = (const float*)d_in[0];
    const float* times  = (const float*)d_in[1];
    const float* W      = (const float*)d_in[2];
    const float* U      = (const float*)d_in[3];
    const float* bias   = (const float*)d_in[4];
    const float* Wc     = (const float*)d_in[5];
    const float* bc     = (const float*)d_in[6];
    float* out = (float*)d_out;
    short* ws  = (short*)d_ws;          // needs 160 KB (Upk 128K + Wpk 32K)

    repack_kernel<<<dim3(40), dim3(256), 0, stream>>>(W, U, ws);
    lstm_mfma<<<dim3(NWG), dim3(512), 0, stream>>>(
        points, times, bias, Wc, bc, out, ws);
}

// Round 9
// 1018.566 us; speedup vs baseline: 2.7048x; 2.7048x over previous
//
#include <hip/hip_runtime.h>

#define HS    128
#define INP   23
#define NGATE 512
#define TLEN  1024
#define BATCH 512
#define MROWS 2
#define NWG   (BATCH / MROWS)   // 256 workgroups -> 1 per CU

typedef short  bf8   __attribute__((ext_vector_type(8)));   // 8 bf16 (4 VGPR)
typedef float  f32x4 __attribute__((ext_vector_type(4)));

__device__ __forceinline__ float fexp(float x) {
    return __builtin_amdgcn_exp2f(x * 1.4426950408889634f);
}
__device__ __forceinline__ float fsigmoid(float x) {
    return __builtin_amdgcn_rcpf(1.0f + fexp(-x));
}
__device__ __forceinline__ float ftanh(float x) {
    return 2.0f * fsigmoid(2.0f * x) - 1.0f;
}
__device__ __forceinline__ short bf16r(float x) {   // round-to-nearest-even
    unsigned u = __float_as_uint(x);
    u += 0x7fffu + ((u >> 16) & 1u);
    return (short)(u >> 16);
}

// ---------------------------------------------------------------------------
// Repack (verbatim from r8 — correctness-verified, absmax 0.0039):
//   Upk[cb<32][s<4][lane<64][e<8] = U[s*32 + 8*(lane>>4)+e][cb*16 + (lane&15)]
//   Wpk[cb<32][lane<64][e<8]      = W[8*(lane>>4)+e][cb*16+(lane&15)], k>=24 -> 0
// ---------------------------------------------------------------------------
__global__ void repack_kernel(const float* __restrict__ W,
                              const float* __restrict__ U,
                              short* __restrict__ ws)
{
    const int id = blockIdx.x * 256 + threadIdx.x;
    short tmp[8];
    if (id < 8192) {
        const int cb = id >> 8, s = (id >> 6) & 3, l = id & 63;
        const int col = cb * 16 + (l & 15);
        const int kb  = s * 32 + ((l >> 4) << 3);
        #pragma unroll
        for (int e = 0; e < 8; ++e) tmp[e] = bf16r(U[(kb + e) * NGATE + col]);
        *(bf8*)(ws + id * 8) = *(const bf8*)tmp;
    } else if (id < 10240) {
        const int id2 = id - 8192;
        const int cb = id2 >> 6, l = id2 & 63;
        const int col = cb * 16 + (l & 15);
        const int kb  = (l >> 4) << 3;
        #pragma unroll
        for (int e = 0; e < 8; ++e)
            tmp[e] = (kb + e < 24) ? bf16r(W[(kb + e) * NGATE + col]) : (short)0;
        *(bf8*)(ws + 65536 + id2 * 8) = *(const bf8*)tmp;
    }
}

// ---------------------------------------------------------------------------
// Main: 256 WGs x 1024 thr (16 waves, 4/SIMD). WG owns batch rows b0, b0+1.
// Wave w owns gate col-blocks cb = {2w, 2w+1}; its 10 B-frags (40 VGPR) are
// loaded ONCE via volatile-asm global_load -> guaranteed register residency
// (the r1/r3/r5/r7 battle, settled). M=2: A-frag rows 0-1 real, 2-15 zero.
// Per step: MFMA -> gate-exchange via LDS -> barrier -> 4 updater waves do
// activations/cell/h-publish/out-proj -> barrier.
// ---------------------------------------------------------------------------
__global__
__attribute__((amdgpu_flat_work_group_size(1024, 1024)))
void lstm_mfma2(const float* __restrict__ points,
                const float* __restrict__ times,
                const float* __restrict__ bias,
                const float* __restrict__ Wc,
                const float* __restrict__ bc,
                float* __restrict__ out,
                const short* __restrict__ ws)
{
    const int wg  = blockIdx.x;
    const int tid = threadIdx.x;
    const int w   = tid >> 6;          // wave 0..15
    const int l   = tid & 63;          // lane
    const int b0  = wg * MROWS;

    __shared__ __align__(16) short hfrag[2][4][64][8];  // 8 KB  A-frag layout
    __shared__ __align__(16) short xfrag[2][64][8];     // 2 KB  A-frag layout
    __shared__ __align__(16) float gates[2][NGATE];     // 4 KB  [row][gate]
    __shared__ float opart[2][4][2];                    // [dbuf][updwave][col]

    const int cb0 = 2 * w, cb1 = 2 * w + 1;
    const float bg0 = bias[cb0 * 16 + (l & 15)];
    const float bg1 = bias[cb1 * 16 + (l & 15)];

    // ---- B-fragments: 10 x 16B loads via volatile asm (pinned in regs) ----
    bf8 u00, u01, u02, u03, u10, u11, u12, u13, wf0, wf1;
    {
        #define LDB(dst, off) { const short* p_ = ws + (off);                 \
            asm volatile("global_load_dwordx4 %0, %1, off"                    \
                         : "=v"(dst) : "v"(p_)); }
        LDB(u00, ((cb0 * 4 + 0) * 64 + l) * 8)
        LDB(u01, ((cb0 * 4 + 1) * 64 + l) * 8)
        LDB(u02, ((cb0 * 4 + 2) * 64 + l) * 8)
        LDB(u03, ((cb0 * 4 + 3) * 64 + l) * 8)
        LDB(u10, ((cb1 * 4 + 0) * 64 + l) * 8)
        LDB(u11, ((cb1 * 4 + 1) * 64 + l) * 8)
        LDB(u12, ((cb1 * 4 + 2) * 64 + l) * 8)
        LDB(u13, ((cb1 * 4 + 3) * 64 + l) * 8)
        LDB(wf0, 65536 + (cb0 * 64 + l) * 8)
        LDB(wf1, 65536 + (cb1 * 64 + l) * 8)
        #undef LDB
        asm volatile("s_waitcnt vmcnt(0)" ::: "memory");
        __builtin_amdgcn_sched_barrier(0);
    }

    // updater state (tid<256: r = tid>>7, j = tid&127)
    const int uj = tid & (HS - 1);
    const float wc0 = Wc[2 * uj], wc1 = Wc[2 * uj + 1];
    const float bc0 = bc[0], bc1 = bc[1];
    float c = 0.0f;

    // ---- init LDS: zero hfrag (rows 2-15 stay zero forever) + xfrag ----
    {
        int* hp = (int*)&hfrag[0][0][0][0];     // 2048 ints
        hp[tid] = 0; hp[tid + 1024] = 0;
        if (tid < 512) ((int*)&xfrag[0][0][0])[tid] = 0;   // 512 ints
    }
    // stage x(t=0): threads 256..303 (wave 4)
    if (tid >= 256 && tid < 256 + MROWS * 24) {
        const int xi = tid - 256, r = xi / 24, f = xi % 24;
        const float v = (f < INP) ? points[((size_t)(b0 + r) * TLEN + 0) * INP + f]
                                  : times[(size_t)(b0 + r) * TLEN + 0];
        xfrag[0][r + ((f >> 3) << 4)][f & 7] = bf16r(v);
    }
    __syncthreads();

    for (int t = 0; t < TLEN; ++t) {
        const int cur = t & 1, nxt = cur ^ 1;

        // issue x(t+1) loads early (wave 4) -> consumed after barrier A
        float xv = 0.0f;
        const bool xown = (tid >= 256 && tid < 256 + MROWS * 24);
        if (t + 1 < TLEN && xown) {
            const int xi = tid - 256, r = xi / 24, f = xi % 24;
            xv = (f < INP) ? points[((size_t)(b0 + r) * TLEN + (t + 1)) * INP + f]
                           : times[(size_t)(b0 + r) * TLEN + (t + 1)];
        }

        // ---- phase 1: A-frags from LDS + 10 MFMAs (2 col-blocks) ----
        const bf8 xa  = *(const bf8*)&xfrag[cur][l][0];
        const bf8 ha0 = *(const bf8*)&hfrag[cur][0][l][0];
        const bf8 ha1 = *(const bf8*)&hfrag[cur][1][l][0];
        const bf8 ha2 = *(const bf8*)&hfrag[cur][2][l][0];
        const bf8 ha3 = *(const bf8*)&hfrag[cur][3][l][0];

        f32x4 a0 = {bg0, bg0, bg0, bg0};
        a0 = __builtin_amdgcn_mfma_f32_16x16x32_bf16(xa,  wf0, a0, 0, 0, 0);
        a0 = __builtin_amdgcn_mfma_f32_16x16x32_bf16(ha0, u00, a0, 0, 0, 0);
        a0 = __builtin_amdgcn_mfma_f32_16x16x32_bf16(ha1, u01, a0, 0, 0, 0);
        a0 = __builtin_amdgcn_mfma_f32_16x16x32_bf16(ha2, u02, a0, 0, 0, 0);
        a0 = __builtin_amdgcn_mfma_f32_16x16x32_bf16(ha3, u03, a0, 0, 0, 0);
        f32x4 a1 = {bg1, bg1, bg1, bg1};
        a1 = __builtin_amdgcn_mfma_f32_16x16x32_bf16(xa,  wf1, a1, 0, 0, 0);
        a1 = __builtin_amdgcn_mfma_f32_16x16x32_bf16(ha0, u10, a1, 0, 0, 0);
        a1 = __builtin_amdgcn_mfma_f32_16x16x32_bf16(ha1, u11, a1, 0, 0, 0);
        a1 = __builtin_amdgcn_mfma_f32_16x16x32_bf16(ha2, u12, a1, 0, 0, 0);
        a1 = __builtin_amdgcn_mfma_f32_16x16x32_bf16(ha3, u13, a1, 0, 0, 0);

        // publish gate pre-activations: D row q (=batch row), col = l (<16)
        if (l < 16) {
            gates[0][cb0 * 16 + l] = a0[0];
            gates[1][cb0 * 16 + l] = a0[1];
            gates[0][cb1 * 16 + l] = a1[0];
            gates[1][cb1 * 16 + l] = a1[1];
        }
        __syncthreads();   // barrier A: gates complete

        // ---- phase 2a: finish output row t-1 (drains during phase 2) ----
        if (t > 0 && tid < 4) {
            const int r = tid >> 1, o = tid & 1;
            const float v = (o ? bc1 : bc0)
                          + opart[nxt][2 * r][o] + opart[nxt][2 * r + 1][o];
            out[(((size_t)(b0 + r)) * TLEN + (t - 1)) * 2 + o] = fsigmoid(v);
        }

        // ---- phase 2b: cell update by waves 0-3 (full 64-lane waves) ----
        if (tid < 2 * HS) {
            const int r = tid >> 7, j = tid & (HS - 1);
            const float ig = fsigmoid(gates[r][j]);
            const float fg = fsigmoid(gates[r][HS + j]);
            const float gg = ftanh(gates[r][2 * HS + j]);
            const float og = fsigmoid(gates[r][3 * HS + j]);
            c = fg * c + ig * gg;
            const float h = og * ftanh(c);
            // h -> A-frag layout: lane' = r + 16*((j>>3)&3), k-step = j>>5
            hfrag[nxt][j >> 5][r + (((j >> 3) & 3) << 4)][j & 7] = bf16r(h);

            // output projection partials (reduce 64 cols of this wave)
            float p0 = h * wc0, p1 = h * wc1;
            #pragma unroll
            for (int off = 32; off; off >>= 1) {
                p0 += __shfl_down(p0, off);
                p1 += __shfl_down(p1, off);
            }
            if (l == 0) { opart[cur][w][0] = p0; opart[cur][w][1] = p1; }
        }

        // ---- phase 2c: stage x(t+1) into LDS ----
        if (t + 1 < TLEN && xown) {
            const int xi = tid - 256, r = xi / 24, f = xi % 24;
            xfrag[nxt][r + ((f >> 3) << 4)][f & 7] = bf16r(xv);
        }
        __syncthreads();   // barrier B: h(t+1), x(t+1), opart ready
    }

    // epilogue: output row TLEN-1 (opart[cur of t=1023] = opart[1])
    if (tid < 4) {
        const int r = tid >> 1, o = tid & 1;
        const float v = (o ? bc1 : bc0)
                      + opart[1][2 * r][o] + opart[1][2 * r + 1][o];
        out[(((size_t)(b0 + r)) * TLEN + (TLEN - 1)) * 2 + o] = fsigmoid(v);
    }
}

extern "C" void kernel_launch(void* const* d_in, const int* in_sizes, int n_in,
                              void* d_out, int out_size, void* d_ws, size_t ws_size,
                              hipStream_t stream) {
    const float* points = (const float*)d_in[0];
    const float* times  = (const float*)d_in[1];
    const float* W      = (const float*)d_in[2];
    const float* U      = (const float*)d_in[3];
    const float* bias   = (const float*)d_in[4];
    const float* Wc     = (const float*)d_in[5];
    const float* bc     = (const float*)d_in[6];
    float* out = (float*)d_out;
    short* ws  = (short*)d_ws;          // 160 KB (Upk 128K + Wpk 32K)

    repack_kernel<<<dim3(40), dim3(256), 0, stream>>>(W, U, ws);
    lstm_mfma2<<<dim3(NWG), dim3(1024), 0, stream>>>(
        points, times, bias, Wc, bc, out, ws);
}